// Round 1
// baseline (320.084 us; speedup 1.0000x reference)
//
#include <hip/hip_runtime.h>

typedef unsigned short ushort_t;
typedef unsigned int uint_t;

typedef short bf16x8 __attribute__((ext_vector_type(8)));
typedef float f32x4 __attribute__((ext_vector_type(4)));

#define MFMA16(a, b, c) __builtin_amdgcn_mfma_f32_16x16x32_bf16(a, b, c, 0, 0, 0)

__device__ __forceinline__ ushort_t f2bf(float f) {
    uint_t u = __float_as_uint(f);
    u += 0x7fffu + ((u >> 16) & 1u);   // RNE
    return (ushort_t)(u >> 16);
}
__device__ __forceinline__ float bf2f(ushort_t h) {
    return __uint_as_float(((uint_t)h) << 16);
}

// async global->LDS, 16B per lane; lds dst must be wave-uniform (HW adds lane*16)
__device__ __forceinline__ void async16(const ushort_t* g, ushort_t* l) {
    __builtin_amdgcn_global_load_lds(
        (const __attribute__((address_space(1))) uint_t*)g,
        (__attribute__((address_space(3))) uint_t*)l, 16, 0, 0);
}

// ---------------- K0a: const_h[h] = bs1[h] + Ws1[h,256:512] . virtual  (fp32)
__global__ void k_consth(const float* __restrict__ Ws1, const float* __restrict__ bs1,
                         const float* __restrict__ virt, float* __restrict__ consth) {
    int h = threadIdx.x;
    if (h >= 128) return;
    const float* row = Ws1 + h * 512 + 256;
    float s = bs1[h];
    for (int d = 0; d < 256; ++d) s += row[d] * virt[d];
    consth[h] = s;
}

// ---------------- K0b: fp32 matrix (rows x 256, row stride src_stride) -> blocked bf16 hi (+lo)
// blocked flat (in 8-elem units): ((row/16)*32 + k/8)*16 + row%16
__global__ void k_convert(const float* __restrict__ src, int src_stride,
                          ushort_t* __restrict__ dhi, ushort_t* __restrict__ dlo, int rows) {
    int tid = blockIdx.x * blockDim.x + threadIdx.x;
    int total = rows * 32;
    if (tid >= total) return;
    int pl = tid & 15, kc = (tid >> 4) & 31, pt = tid >> 9;
    int row = pt * 16 + pl;
    const float* s = src + (size_t)row * src_stride + kc * 8;
    ushort_t hs[8], ls[8];
#pragma unroll
    for (int j = 0; j < 8; ++j) {
        float v = s[j];
        ushort_t h = f2bf(v);
        hs[j] = h;
        ls[j] = f2bf(v - bf2f(h));
    }
    uint4 hv;
    hv.x = hs[0] | ((uint_t)hs[1] << 16); hv.y = hs[2] | ((uint_t)hs[3] << 16);
    hv.z = hs[4] | ((uint_t)hs[5] << 16); hv.w = hs[6] | ((uint_t)hs[7] << 16);
    *(uint4*)(dhi + (size_t)tid * 8) = hv;
    if (dlo) {
        uint4 lv;
        lv.x = ls[0] | ((uint_t)ls[1] << 16); lv.y = ls[2] | ((uint_t)ls[3] << 16);
        lv.z = ls[4] | ((uint_t)ls[5] << 16); lv.w = ls[6] | ((uint_t)ls[7] << 16);
        *(uint4*)(dlo + (size_t)tid * 8) = lv;
    }
}

// ---------------- K1: h_events = q_tab[q] + r_tab[r] + [sin|cos](t*div) -> blocked bf16 hi/lo
// wave handles one ptile (16 positions); lane = (kq 0..3, pl 0..15); 8 iters cover k=0..255
__global__ void k_embed(const int* __restrict__ q_seq, const int* __restrict__ r_seq,
                        const float* __restrict__ t_seq, const float* __restrict__ q_tab,
                        const float* __restrict__ r_tab,
                        ushort_t* __restrict__ h_hi, ushort_t* __restrict__ h_lo) {
    __shared__ float sdiv[128];
    int tid = threadIdx.x;
    if (tid < 128) sdiv[tid] = expf((float)tid * -0.07195578415606394f); // -ln(10000)/128
    __syncthreads();
    int w = tid >> 6, lane = tid & 63;
    int pl = lane & 15, kq = lane >> 4;
    int ptile = blockIdx.x * 4 + w;
    int p = ptile * 16 + pl;
    int q = q_seq[p], r = r_seq[p];
    float tt = t_seq[p];
    const float4* qrow = (const float4*)(q_tab + (size_t)q * 256);
    const float4* rrow = (const float4*)(r_tab + (size_t)r * 256);
#pragma unroll
    for (int it = 0; it < 8; ++it) {
        int kc = it * 4 + kq;
        int k0 = kc * 8;
        float4 qa = qrow[kc * 2], qb = qrow[kc * 2 + 1];
        float4 ra = rrow[kc * 2], rb = rrow[kc * 2 + 1];
        float v[8] = {qa.x + ra.x, qa.y + ra.y, qa.z + ra.z, qa.w + ra.w,
                      qb.x + rb.x, qb.y + rb.y, qb.z + rb.z, qb.w + rb.w};
        bool iscos = (kc >= 16);
#pragma unroll
        for (int j = 0; j < 8; ++j) {
            float ang = tt * sdiv[(k0 + j) & 127];
            v[j] += iscos ? cosf(ang) : sinf(ang);
        }
        ushort_t hs[8], ls[8];
#pragma unroll
        for (int j = 0; j < 8; ++j) {
            ushort_t h = f2bf(v[j]);
            hs[j] = h;
            ls[j] = f2bf(v[j] - bf2f(h));
        }
        size_t off = ((size_t)(ptile * 32 + kc) * 16 + pl) * 8;
        uint4 hv, lv;
        hv.x = hs[0] | ((uint_t)hs[1] << 16); hv.y = hs[2] | ((uint_t)hs[3] << 16);
        hv.z = hs[4] | ((uint_t)hs[5] << 16); hv.w = hs[6] | ((uint_t)hs[7] << 16);
        lv.x = ls[0] | ((uint_t)ls[1] << 16); lv.y = ls[2] | ((uint_t)ls[3] << 16);
        lv.z = ls[4] | ((uint_t)ls[5] << 16); lv.w = ls[6] | ((uint_t)ls[7] << 16);
        *(uint4*)(h_hi + off) = hv;
        *(uint4*)(h_lo + off) = lv;
    }
}

// ---------------- K2: struct head. M-tile 64 x N=128 x K=256, split-bf16 (3 MFMAs),
// fused epilogue: +const_h, leaky, .Ws2, sigmoid(x*100)*mask -> A_hat
__global__ __launch_bounds__(256, 2) void k_struct(
    const ushort_t* __restrict__ h_hi, const ushort_t* __restrict__ h_lo,
    const ushort_t* __restrict__ ws1h, const ushort_t* __restrict__ ws1l,
    const float* __restrict__ consth, const float* __restrict__ Ws2,
    const float* __restrict__ bs2, const float* __restrict__ mask,
    float* __restrict__ out_ahat) {
    __shared__ ushort_t sAhi[16384];
    __shared__ ushort_t sAlo[16384];
    __shared__ float sLogit[64];
    int tid = threadIdx.x;
    int w = tid >> 6, lane = tid & 63, nl = lane & 15, kq = lane >> 4;
    if (tid < 64) sLogit[tid] = 0.0f;
    int pt0 = blockIdx.x * 4;  // 4 ptiles = 64 positions
    const ushort_t* gHi = h_hi + (size_t)pt0 * 4096;
    const ushort_t* gLo = h_lo + (size_t)pt0 * 4096;
#pragma unroll
    for (int i = 0; i < 8; ++i) {
        int c = w * 8 + i;
        async16(gHi + c * 512 + lane * 8, &sAhi[c * 512]);
        async16(gLo + c * 512 + lane * 8, &sAlo[c * 512]);
    }
    // B fragments (Ws1 hi/lo) preloaded to registers; wave owns n-range w*32..w*32+31
    bf16x8 Bhi[2][8], Blo[2][8];
#pragma unroll
    for (int nt = 0; nt < 2; ++nt) {
        int ntg = w * 2 + nt;
#pragma unroll
        for (int ks = 0; ks < 8; ++ks) {
            int off = ((ntg * 32 + ks * 4 + kq) * 16 + nl) * 8;
            Bhi[nt][ks] = *(const bf16x8*)(ws1h + off);
            Blo[nt][ks] = *(const bf16x8*)(ws1l + off);
        }
    }
    __syncthreads();
    f32x4 acc[4][2];
    f32x4 z4 = {0.f, 0.f, 0.f, 0.f};
#pragma unroll
    for (int mt = 0; mt < 4; ++mt)
#pragma unroll
        for (int nt = 0; nt < 2; ++nt) acc[mt][nt] = z4;
#pragma unroll
    for (int ks = 0; ks < 8; ++ks) {
        bf16x8 ahi[4], alo[4];
#pragma unroll
        for (int mt = 0; mt < 4; ++mt) {
            int off = ((mt * 32 + ks * 4 + kq) * 16 + nl) * 8;
            ahi[mt] = *(const bf16x8*)&sAhi[off];
            alo[mt] = *(const bf16x8*)&sAlo[off];
        }
#pragma unroll
        for (int mt = 0; mt < 4; ++mt)
#pragma unroll
            for (int nt = 0; nt < 2; ++nt) {
                acc[mt][nt] = MFMA16(ahi[mt], Bhi[nt][ks], acc[mt][nt]);
                acc[mt][nt] = MFMA16(alo[mt], Bhi[nt][ks], acc[mt][nt]);
                acc[mt][nt] = MFMA16(ahi[mt], Blo[nt][ks], acc[mt][nt]);
            }
    }
    // epilogue: hdn = leaky(acc + const_h); partial logits = hdn * Ws2
    float ps[4][4];
#pragma unroll
    for (int mt = 0; mt < 4; ++mt)
#pragma unroll
        for (int r = 0; r < 4; ++r) ps[mt][r] = 0.f;
#pragma unroll
    for (int nt = 0; nt < 2; ++nt) {
        int ng = w * 32 + nt * 16 + nl;
        float chv = consth[ng], w2 = Ws2[ng];
#pragma unroll
        for (int mt = 0; mt < 4; ++mt)
#pragma unroll
            for (int r = 0; r < 4; ++r) {
                float v = acc[mt][nt][r] + chv;
                v = v > 0.f ? v : 0.2f * v;
                ps[mt][r] += v * w2;
            }
    }
#pragma unroll
    for (int mt = 0; mt < 4; ++mt)
#pragma unroll
        for (int r = 0; r < 4; ++r) {
            float x = ps[mt][r];
            x += __shfl_xor(x, 1, 64);
            x += __shfl_xor(x, 2, 64);
            x += __shfl_xor(x, 4, 64);
            x += __shfl_xor(x, 8, 64);
            ps[mt][r] = x;
        }
    if (nl == 0) {
#pragma unroll
        for (int mt = 0; mt < 4; ++mt)
#pragma unroll
            for (int r = 0; r < 4; ++r)
                atomicAdd(&sLogit[mt * 16 + kq * 4 + r], ps[mt][r]);
    }
    __syncthreads();
    if (tid < 64) {
        int p = pt0 * 16 + tid;
        float lg = sLogit[tid] + bs2[0];
        float y = lg * 100.0f;
        y = fminf(fmaxf(y, -60.f), 60.f);
        float a = 1.0f / (1.0f + expf(-y));
        out_ahat[p] = a * mask[p];
    }
}

// ---------------- K3: Wa GEMM (bf16 MFMA) with fused leaky + A_hat weighting + L-reduce
// grid: (mtile128, nchunk128); per wave 64x64; BK=128, two staged halves
__global__ __launch_bounds__(256, 2) void k_agg(
    const ushort_t* __restrict__ h_hi, const ushort_t* __restrict__ wa_blk,
    const float* __restrict__ ba, const float* __restrict__ ahat,
    float* __restrict__ u_i) {
    __shared__ ushort_t sA[16384];  // [ptl8][kc16][pl16][8]
    __shared__ ushort_t sB[16384];
    __shared__ float sAh[128];
    int tid = threadIdx.x;
    int w = tid >> 6, lane = tid & 63, nl = lane & 15, kq = lane >> 4;
    int mt128 = blockIdx.x >> 3, nch = blockIdx.x & 7;
    int p0 = mt128 * 128, n0 = nch * 128, bidx = p0 >> 11;
    if (tid < 128) sAh[tid] = ahat[p0 + tid];
    int mh = w & 1, nh = w >> 1;
    const ushort_t* gA = h_hi + (size_t)(p0 >> 4) * 4096;
    const ushort_t* gB = wa_blk + (size_t)(n0 >> 4) * 4096;
    f32x4 acc[4][4];
    f32x4 z4 = {0.f, 0.f, 0.f, 0.f};
#pragma unroll
    for (int mt = 0; mt < 4; ++mt)
#pragma unroll
        for (int nt = 0; nt < 4; ++nt) acc[mt][nt] = z4;
    for (int kh = 0; kh < 2; ++kh) {
#pragma unroll
        for (int i = 0; i < 16; ++i) {
            int gi = w * 16 + i;
            int isB = gi >> 5;
            int loc = gi & 31;
            int tl = loc >> 2, sub = loc & 3;
            const ushort_t* src = (isB ? gB : gA) +
                                  ((size_t)tl * 32 + kh * 16) * 128 + sub * 512 + lane * 8;
            ushort_t* dst = (isB ? sB : sA) + tl * 2048 + sub * 512;
            async16(src, dst);
        }
        __syncthreads();
#pragma unroll
        for (int ks = 0; ks < 4; ++ks) {
            bf16x8 af[4], bfr[4];
#pragma unroll
            for (int mt = 0; mt < 4; ++mt) {
                int ptl = mh * 4 + mt;
                af[mt] = *(const bf16x8*)&sA[(ptl * 256 + (ks * 4 + kq) * 16 + nl) * 8];
            }
#pragma unroll
            for (int nt = 0; nt < 4; ++nt) {
                int ntl = nh * 4 + nt;
                bfr[nt] = *(const bf16x8*)&sB[(ntl * 256 + (ks * 4 + kq) * 16 + nl) * 8];
            }
#pragma unroll
            for (int mt = 0; mt < 4; ++mt)
#pragma unroll
                for (int nt = 0; nt < 4; ++nt)
                    acc[mt][nt] = MFMA16(af[mt], bfr[nt], acc[mt][nt]);
        }
        __syncthreads();
    }
    // epilogue: leaky(acc+ba)*A_hat, reduce over the wave's 64 m-rows, atomicAdd u_i
#pragma unroll
    for (int nt = 0; nt < 4; ++nt) {
        int ng = n0 + nh * 64 + nt * 16 + nl;
        float ban = ba[ng];
        float s = 0.f;
#pragma unroll
        for (int mt = 0; mt < 4; ++mt)
#pragma unroll
            for (int r = 0; r < 4; ++r) {
                float v = acc[mt][nt][r] + ban;
                v = v > 0.f ? v : 0.2f * v;
                int ml = mh * 64 + mt * 16 + kq * 4 + r;
                s += v * sAh[ml];
            }
        s += __shfl_xor(s, 16, 64);
        s += __shfl_xor(s, 32, 64);
        if (kq == 0) atomicAdd(&u_i[bidx * 1024 + ng], s);
    }
}

extern "C" void kernel_launch(void* const* d_in, const int* in_sizes, int n_in,
                              void* d_out, int out_size, void* d_ws, size_t ws_size,
                              hipStream_t stream) {
    const int* q_seq = (const int*)d_in[0];
    const int* r_seq = (const int*)d_in[1];
    const float* t_seq = (const float*)d_in[2];
    const float* mask = (const float*)d_in[3];
    const float* q_tab = (const float*)d_in[4];
    const float* r_tab = (const float*)d_in[5];
    const float* virt = (const float*)d_in[6];
    const float* Ws1 = (const float*)d_in[7];
    const float* bs1 = (const float*)d_in[8];
    const float* Ws2 = (const float*)d_in[9];
    const float* bs2 = (const float*)d_in[10];
    const float* Wa = (const float*)d_in[11];
    const float* ba = (const float*)d_in[12];
    float* out = (float*)d_out;

    // ws layout
    ushort_t* h_hi = (ushort_t*)d_ws;            // 131072*256 bf16
    ushort_t* h_lo = h_hi + 33554432;
    ushort_t* wa_b = h_lo + 33554432;            // 1024*256 bf16 blocked
    ushort_t* ws1h = wa_b + 262144;              // 128*256 bf16 blocked
    ushort_t* ws1l = ws1h + 32768;
    float* ch = (float*)(ws1l + 32768);          // 128 f32

    hipMemsetAsync(out, 0, 65536 * sizeof(float), stream);  // zero u_i
    hipLaunchKernelGGL(k_consth, dim3(1), dim3(128), 0, stream, Ws1, bs1, virt, ch);
    hipLaunchKernelGGL(k_convert, dim3(128), dim3(256), 0, stream,
                       Wa, 256, wa_b, (ushort_t*)nullptr, 1024);
    hipLaunchKernelGGL(k_convert, dim3(16), dim3(256), 0, stream,
                       Ws1, 512, ws1h, ws1l, 128);
    hipLaunchKernelGGL(k_embed, dim3(2048), dim3(256), 0, stream,
                       q_seq, r_seq, t_seq, q_tab, r_tab, h_hi, h_lo);
    hipLaunchKernelGGL(k_struct, dim3(2048), dim3(256), 0, stream,
                       h_hi, h_lo, ws1h, ws1l, ch, Ws2, bs2, mask, out + 65536);
    hipLaunchKernelGGL(k_agg, dim3(8192), dim3(256), 0, stream,
                       h_hi, wa_b, ba, out + 65536, out);
}

// Round 2
// 287.717 us; speedup vs baseline: 1.1125x; 1.1125x over previous
//
#include <hip/hip_runtime.h>

typedef unsigned short ushort_t;
typedef unsigned int uint_t;

typedef short bf16x8 __attribute__((ext_vector_type(8)));
typedef float f32x4 __attribute__((ext_vector_type(4)));

#define MFMA16(a, b, c) __builtin_amdgcn_mfma_f32_16x16x32_bf16(a, b, c, 0, 0, 0)

__device__ __forceinline__ ushort_t f2bf(float f) {
    uint_t u = __float_as_uint(f);
    u += 0x7fffu + ((u >> 16) & 1u);   // RNE
    return (ushort_t)(u >> 16);
}
__device__ __forceinline__ float bf2f(ushort_t h) {
    return __uint_as_float(((uint_t)h) << 16);
}

// async global->LDS, 16B per lane; lds dst must be wave-uniform (HW adds lane*16)
__device__ __forceinline__ void async16(const ushort_t* g, ushort_t* l) {
    __builtin_amdgcn_global_load_lds(
        (const __attribute__((address_space(1))) uint_t*)g,
        (__attribute__((address_space(3))) uint_t*)l, 16, 0, 0);
}

// ---------------- K0a: const_h[h] = bs1[h] + Ws1[h,256:512] . virtual  (fp32)
__global__ void k_consth(const float* __restrict__ Ws1, const float* __restrict__ bs1,
                         const float* __restrict__ virt, float* __restrict__ consth) {
    int h = threadIdx.x;
    if (h >= 128) return;
    const float* row = Ws1 + h * 512 + 256;
    float s = bs1[h];
    for (int d = 0; d < 256; ++d) s += row[d] * virt[d];
    consth[h] = s;
}

// ---------------- K0b: fp32 matrix (rows x 256, row stride src_stride) -> blocked bf16 hi (+lo)
// blocked flat (in 8-elem units): ((row/16)*32 + k/8)*16 + row%16
__global__ void k_convert(const float* __restrict__ src, int src_stride,
                          ushort_t* __restrict__ dhi, ushort_t* __restrict__ dlo, int rows) {
    int tid = blockIdx.x * blockDim.x + threadIdx.x;
    int total = rows * 32;
    if (tid >= total) return;
    int pl = tid & 15, kc = (tid >> 4) & 31, pt = tid >> 9;
    int row = pt * 16 + pl;
    const float* s = src + (size_t)row * src_stride + kc * 8;
    ushort_t hs[8], ls[8];
#pragma unroll
    for (int j = 0; j < 8; ++j) {
        float v = s[j];
        ushort_t h = f2bf(v);
        hs[j] = h;
        ls[j] = f2bf(v - bf2f(h));
    }
    uint4 hv;
    hv.x = hs[0] | ((uint_t)hs[1] << 16); hv.y = hs[2] | ((uint_t)hs[3] << 16);
    hv.z = hs[4] | ((uint_t)hs[5] << 16); hv.w = hs[6] | ((uint_t)hs[7] << 16);
    *(uint4*)(dhi + (size_t)tid * 8) = hv;
    if (dlo) {
        uint4 lv;
        lv.x = ls[0] | ((uint_t)ls[1] << 16); lv.y = ls[2] | ((uint_t)ls[3] << 16);
        lv.z = ls[4] | ((uint_t)ls[5] << 16); lv.w = ls[6] | ((uint_t)ls[7] << 16);
        *(uint4*)(dlo + (size_t)tid * 8) = lv;
    }
}

// ---------------- K1: FUSED embed + struct head.
// Each wave: one ptile (16 positions). Gather + trig -> hi/lo fragments in registers
// (already in MFMA A-layout) -> write hi to global h_hi + hi/lo to LDS.
// Then block-wide split-bf16 MFMA (64 pos x 128 h x 256 k) + fused epilogue:
// +const_h, leaky, .Ws2, sigmoid(x*100)*mask -> A_hat.  h_lo never hits HBM.
__global__ __launch_bounds__(256, 2) void k_embed_struct(
    const int* __restrict__ q_seq, const int* __restrict__ r_seq,
    const float* __restrict__ t_seq, const float* __restrict__ q_tab,
    const float* __restrict__ r_tab,
    const ushort_t* __restrict__ ws1h, const ushort_t* __restrict__ ws1l,
    const float* __restrict__ consth, const float* __restrict__ Ws2,
    const float* __restrict__ bs2, const float* __restrict__ mask,
    ushort_t* __restrict__ h_hi, float* __restrict__ out_ahat) {
    __shared__ ushort_t sAhi[16384];   // 64 pos x 256 k, blocked
    __shared__ ushort_t sAlo[16384];
    __shared__ float sdiv[128];
    __shared__ float sLogit[64];
    int tid = threadIdx.x;
    if (tid < 128) sdiv[tid] = expf((float)tid * -0.07195578415606394f); // -ln(10000)/128
    if (tid < 64) sLogit[tid] = 0.0f;
    int w = tid >> 6, lane = tid & 63;
    int pl = lane & 15, kq = lane >> 4;
    int nl = pl;
    int ptile = blockIdx.x * 4 + w;
    int p = ptile * 16 + pl;
    int q = q_seq[p], r = r_seq[p];
    float tt = t_seq[p];
    const float4* qrow = (const float4*)(q_tab + (size_t)q * 256);
    const float4* rrow = (const float4*)(r_tab + (size_t)r * 256);
    // B fragments (Ws1 hi/lo); wave owns n-range w*32..w*32+31
    bf16x8 Bhi[2][8], Blo[2][8];
#pragma unroll
    for (int nt = 0; nt < 2; ++nt) {
        int ntg = w * 2 + nt;
#pragma unroll
        for (int ks = 0; ks < 8; ++ks) {
            int off = ((ntg * 32 + ks * 4 + kq) * 16 + nl) * 8;
            Bhi[nt][ks] = *(const bf16x8*)(ws1h + off);
            Blo[nt][ks] = *(const bf16x8*)(ws1l + off);
        }
    }
    __syncthreads();  // sdiv + sLogit ready
#pragma unroll
    for (int it = 0; it < 8; ++it) {
        int kc = it * 4 + kq;
        int k0 = kc * 8;
        float4 qa = qrow[kc * 2], qb = qrow[kc * 2 + 1];
        float4 ra = rrow[kc * 2], rb = rrow[kc * 2 + 1];
        float v[8] = {qa.x + ra.x, qa.y + ra.y, qa.z + ra.z, qa.w + ra.w,
                      qb.x + rb.x, qb.y + rb.y, qb.z + rb.z, qb.w + rb.w};
        bool iscos = (kc >= 16);
#pragma unroll
        for (int j = 0; j < 8; ++j) {
            float ang = tt * sdiv[(k0 + j) & 127];
            v[j] += iscos ? cosf(ang) : sinf(ang);
        }
        ushort_t hs[8], ls[8];
#pragma unroll
        for (int j = 0; j < 8; ++j) {
            ushort_t h = f2bf(v[j]);
            hs[j] = h;
            ls[j] = f2bf(v[j] - bf2f(h));
        }
        uint4 hv, lv;
        hv.x = hs[0] | ((uint_t)hs[1] << 16); hv.y = hs[2] | ((uint_t)hs[3] << 16);
        hv.z = hs[4] | ((uint_t)hs[5] << 16); hv.w = hs[6] | ((uint_t)hs[7] << 16);
        lv.x = ls[0] | ((uint_t)ls[1] << 16); lv.y = ls[2] | ((uint_t)ls[3] << 16);
        lv.z = ls[4] | ((uint_t)ls[5] << 16); lv.w = ls[6] | ((uint_t)ls[7] << 16);
        *(uint4*)(h_hi + ((size_t)(ptile * 32 + kc) * 16 + pl) * 8) = hv;
        int loff = ((w * 32 + kc) * 16 + pl) * 8;
        *(uint4*)(sAhi + loff) = hv;
        *(uint4*)(sAlo + loff) = lv;
    }
    __syncthreads();  // fragments visible block-wide
    f32x4 acc[4][2];
    f32x4 z4 = {0.f, 0.f, 0.f, 0.f};
#pragma unroll
    for (int mt = 0; mt < 4; ++mt)
#pragma unroll
        for (int nt = 0; nt < 2; ++nt) acc[mt][nt] = z4;
#pragma unroll
    for (int ks = 0; ks < 8; ++ks) {
        bf16x8 ahi[4], alo[4];
#pragma unroll
        for (int mt = 0; mt < 4; ++mt) {
            int off = ((mt * 32 + ks * 4 + kq) * 16 + nl) * 8;
            ahi[mt] = *(const bf16x8*)&sAhi[off];
            alo[mt] = *(const bf16x8*)&sAlo[off];
        }
#pragma unroll
        for (int mt = 0; mt < 4; ++mt)
#pragma unroll
            for (int nt = 0; nt < 2; ++nt) {
                acc[mt][nt] = MFMA16(ahi[mt], Bhi[nt][ks], acc[mt][nt]);
                acc[mt][nt] = MFMA16(alo[mt], Bhi[nt][ks], acc[mt][nt]);
                acc[mt][nt] = MFMA16(ahi[mt], Blo[nt][ks], acc[mt][nt]);
            }
    }
    // epilogue: hdn = leaky(acc + const_h); partial logits = hdn * Ws2
    float ps[4][4];
#pragma unroll
    for (int mt = 0; mt < 4; ++mt)
#pragma unroll
        for (int r = 0; r < 4; ++r) ps[mt][r] = 0.f;
#pragma unroll
    for (int nt = 0; nt < 2; ++nt) {
        int ng = w * 32 + nt * 16 + nl;
        float chv = consth[ng], w2 = Ws2[ng];
#pragma unroll
        for (int mt = 0; mt < 4; ++mt)
#pragma unroll
            for (int r = 0; r < 4; ++r) {
                float v = acc[mt][nt][r] + chv;
                v = v > 0.f ? v : 0.2f * v;
                ps[mt][r] += v * w2;
            }
    }
#pragma unroll
    for (int mt = 0; mt < 4; ++mt)
#pragma unroll
        for (int r = 0; r < 4; ++r) {
            float x = ps[mt][r];
            x += __shfl_xor(x, 1, 64);
            x += __shfl_xor(x, 2, 64);
            x += __shfl_xor(x, 4, 64);
            x += __shfl_xor(x, 8, 64);
            ps[mt][r] = x;
        }
    if (nl == 0) {
#pragma unroll
        for (int mt = 0; mt < 4; ++mt)
#pragma unroll
            for (int r = 0; r < 4; ++r)
                atomicAdd(&sLogit[mt * 16 + kq * 4 + r], ps[mt][r]);
    }
    __syncthreads();
    if (tid < 64) {
        int pp = blockIdx.x * 64 + tid;
        float lg = sLogit[tid] + bs2[0];
        float y = lg * 100.0f;
        y = fminf(fmaxf(y, -60.f), 60.f);
        float a = 1.0f / (1.0f + expf(-y));
        out_ahat[pp] = a * mask[pp];
    }
}

// ---------------- K2: Wa GEMM (bf16 MFMA) with fused leaky + A_hat weighting + L-reduce.
// One block per 128-position M-tile; loops over all 8 N-chunks internally so
// A-tile re-reads hit the same XCD's L2 (HBM fetch ~264MB -> ~75MB).
__global__ __launch_bounds__(256, 2) void k_agg(
    const ushort_t* __restrict__ h_hi, const ushort_t* __restrict__ wa_blk,
    const float* __restrict__ ba, const float* __restrict__ ahat,
    float* __restrict__ u_i) {
    __shared__ ushort_t sA[16384];  // [ptl8][kc16][pl16][8]  (half-K)
    __shared__ ushort_t sB[16384];
    __shared__ float sAh[128];
    int tid = threadIdx.x;
    int w = tid >> 6, lane = tid & 63, nl = lane & 15, kq = lane >> 4;
    int p0 = blockIdx.x * 128, bidx = p0 >> 11;
    if (tid < 128) sAh[tid] = ahat[p0 + tid];
    int mh = w & 1, nh = w >> 1;
    const ushort_t* gA = h_hi + (size_t)(p0 >> 4) * 4096;
    for (int nch = 0; nch < 8; ++nch) {
        const ushort_t* gB = wa_blk + (size_t)nch * 8 * 4096;
        int n0 = nch * 128;
        f32x4 acc[4][4];
        f32x4 z4 = {0.f, 0.f, 0.f, 0.f};
#pragma unroll
        for (int mt = 0; mt < 4; ++mt)
#pragma unroll
            for (int nt = 0; nt < 4; ++nt) acc[mt][nt] = z4;
        for (int kh = 0; kh < 2; ++kh) {
#pragma unroll
            for (int i = 0; i < 16; ++i) {
                int gi = w * 16 + i;
                int isB = gi >> 5;
                int loc = gi & 31;
                int tl = loc >> 2, sub = loc & 3;
                const ushort_t* src = (isB ? gB : gA) +
                                      ((size_t)tl * 32 + kh * 16) * 128 + sub * 512 + lane * 8;
                ushort_t* dst = (isB ? sB : sA) + tl * 2048 + sub * 512;
                async16(src, dst);
            }
            __syncthreads();
#pragma unroll
            for (int ks = 0; ks < 4; ++ks) {
                bf16x8 af[4], bfr[4];
#pragma unroll
                for (int mt = 0; mt < 4; ++mt) {
                    int ptl = mh * 4 + mt;
                    af[mt] = *(const bf16x8*)&sA[(ptl * 256 + (ks * 4 + kq) * 16 + nl) * 8];
                }
#pragma unroll
                for (int nt = 0; nt < 4; ++nt) {
                    int ntl = nh * 4 + nt;
                    bfr[nt] = *(const bf16x8*)&sB[(ntl * 256 + (ks * 4 + kq) * 16 + nl) * 8];
                }
#pragma unroll
                for (int mt = 0; mt < 4; ++mt)
#pragma unroll
                    for (int nt = 0; nt < 4; ++nt)
                        acc[mt][nt] = MFMA16(af[mt], bfr[nt], acc[mt][nt]);
            }
            __syncthreads();
        }
        // epilogue: leaky(acc+ba)*A_hat, reduce over the wave's 64 m-rows, atomicAdd u_i
#pragma unroll
        for (int nt = 0; nt < 4; ++nt) {
            int ng = n0 + nh * 64 + nt * 16 + nl;
            float ban = ba[ng];
            float s = 0.f;
#pragma unroll
            for (int mt = 0; mt < 4; ++mt)
#pragma unroll
                for (int r = 0; r < 4; ++r) {
                    float v = acc[mt][nt][r] + ban;
                    v = v > 0.f ? v : 0.2f * v;
                    int ml = mh * 64 + mt * 16 + kq * 4 + r;
                    s += v * sAh[ml];
                }
            s += __shfl_xor(s, 16, 64);
            s += __shfl_xor(s, 32, 64);
            if (kq == 0) atomicAdd(&u_i[bidx * 1024 + ng], s);
        }
    }
}

extern "C" void kernel_launch(void* const* d_in, const int* in_sizes, int n_in,
                              void* d_out, int out_size, void* d_ws, size_t ws_size,
                              hipStream_t stream) {
    const int* q_seq = (const int*)d_in[0];
    const int* r_seq = (const int*)d_in[1];
    const float* t_seq = (const float*)d_in[2];
    const float* mask = (const float*)d_in[3];
    const float* q_tab = (const float*)d_in[4];
    const float* r_tab = (const float*)d_in[5];
    const float* virt = (const float*)d_in[6];
    const float* Ws1 = (const float*)d_in[7];
    const float* bs1 = (const float*)d_in[8];
    const float* Ws2 = (const float*)d_in[9];
    const float* bs2 = (const float*)d_in[10];
    const float* Wa = (const float*)d_in[11];
    const float* ba = (const float*)d_in[12];
    float* out = (float*)d_out;

    // ws layout
    ushort_t* h_hi = (ushort_t*)d_ws;            // 131072*256 bf16 blocked
    ushort_t* wa_b = h_hi + 33554432;            // 1024*256 bf16 blocked
    ushort_t* ws1h = wa_b + 262144;              // 128*256 bf16 blocked
    ushort_t* ws1l = ws1h + 32768;
    float* ch = (float*)(ws1l + 32768);          // 128 f32

    hipMemsetAsync(out, 0, 65536 * sizeof(float), stream);  // zero u_i
    hipLaunchKernelGGL(k_consth, dim3(1), dim3(128), 0, stream, Ws1, bs1, virt, ch);
    hipLaunchKernelGGL(k_convert, dim3(128), dim3(256), 0, stream,
                       Wa, 256, wa_b, (ushort_t*)nullptr, 1024);
    hipLaunchKernelGGL(k_convert, dim3(16), dim3(256), 0, stream,
                       Ws1, 512, ws1h, ws1l, 128);
    hipLaunchKernelGGL(k_embed_struct, dim3(2048), dim3(256), 0, stream,
                       q_seq, r_seq, t_seq, q_tab, r_tab, ws1h, ws1l, ch, Ws2, bs2,
                       mask, h_hi, out + 65536);
    hipLaunchKernelGGL(k_agg, dim3(1024), dim3(256), 0, stream,
                       h_hi, wa_b, ba, out + 65536, out);
}

// Round 3
// 273.230 us; speedup vs baseline: 1.1715x; 1.0530x over previous
//
#include <hip/hip_runtime.h>

typedef unsigned short ushort_t;
typedef unsigned int uint_t;

typedef short bf16x8 __attribute__((ext_vector_type(8)));
typedef float f32x4 __attribute__((ext_vector_type(4)));

#define MFMA16(a, b, c) __builtin_amdgcn_mfma_f32_16x16x32_bf16(a, b, c, 0, 0, 0)

__device__ __forceinline__ ushort_t f2bf(float f) {
    uint_t u = __float_as_uint(f);
    u += 0x7fffu + ((u >> 16) & 1u);   // RNE
    return (ushort_t)(u >> 16);
}
__device__ __forceinline__ float bf2f(ushort_t h) {
    return __uint_as_float(((uint_t)h) << 16);
}

// async global->LDS, 16B per lane; lds dst is wave-uniform (HW adds lane*16)
__device__ __forceinline__ void async16(const ushort_t* g, ushort_t* l) {
    __builtin_amdgcn_global_load_lds(
        (const __attribute__((address_space(1))) uint_t*)g,
        (__attribute__((address_space(3))) uint_t*)l, 16, 0, 0);
}

// ---------------- K0: fused prep. block0: const_h; blocks 1..128: Wa->bf16 blocked;
// blocks 129..144: Ws1[:, :256] -> bf16 hi/lo blocked.
// blocked flat (in 8-elem units): ((row/16)*32 + k/8)*16 + row%16
__global__ void k_prep(const float* __restrict__ Ws1, const float* __restrict__ bs1,
                       const float* __restrict__ virt, const float* __restrict__ Wa,
                       float* __restrict__ consth, ushort_t* __restrict__ wa_b,
                       ushort_t* __restrict__ ws1h, ushort_t* __restrict__ ws1l) {
    int b = blockIdx.x;
    if (b == 0) {
        int h = threadIdx.x;
        if (h < 128) {
            const float* row = Ws1 + h * 512 + 256;
            float s = bs1[h];
            for (int d = 0; d < 256; ++d) s += row[d] * virt[d];
            consth[h] = s;
        }
        return;
    }
    const float* src;
    int src_stride, tid;
    ushort_t *dhi, *dlo;
    if (b <= 128) {
        tid = (b - 1) * 256 + threadIdx.x;   // 1024 rows * 32 = 32768 tids
        src = Wa; src_stride = 256; dhi = wa_b; dlo = nullptr;
    } else {
        tid = (b - 129) * 256 + threadIdx.x; // 128 rows * 32 = 4096 tids
        src = Ws1; src_stride = 512; dhi = ws1h; dlo = ws1l;
    }
    int pl = tid & 15, kc = (tid >> 4) & 31, pt = tid >> 9;
    int row = pt * 16 + pl;
    const float* s = src + (size_t)row * src_stride + kc * 8;
    ushort_t hs[8], ls[8];
#pragma unroll
    for (int j = 0; j < 8; ++j) {
        float v = s[j];
        ushort_t h = f2bf(v);
        hs[j] = h;
        ls[j] = f2bf(v - bf2f(h));
    }
    uint4 hv;
    hv.x = hs[0] | ((uint_t)hs[1] << 16); hv.y = hs[2] | ((uint_t)hs[3] << 16);
    hv.z = hs[4] | ((uint_t)hs[5] << 16); hv.w = hs[6] | ((uint_t)hs[7] << 16);
    *(uint4*)(dhi + (size_t)tid * 8) = hv;
    if (dlo) {
        uint4 lv;
        lv.x = ls[0] | ((uint_t)ls[1] << 16); lv.y = ls[2] | ((uint_t)ls[3] << 16);
        lv.z = ls[4] | ((uint_t)ls[5] << 16); lv.w = ls[6] | ((uint_t)ls[7] << 16);
        *(uint4*)(dlo + (size_t)tid * 8) = lv;
    }
}

// ---------------- K1: FUSED embed + struct head.
// Phase 1: async16-stage the 64 q-rows into LDS (coalesced row DMA, stride 1040B pad).
// Phase 2: per-lane transpose reads from LDS + r_tab(L1) + fast trig -> hi/lo fragments
//          (MFMA A-layout) -> global h_hi + LDS frag exchange.
// Phase 3: split-bf16 MFMA (3 terms) with software-pipelined per-ks B loads from global,
//          fused +const_h, leaky, .Ws2, sigmoid(x*100)*mask -> A_hat.
__global__ __launch_bounds__(256, 1) void k_embed_struct(
    const int* __restrict__ q_seq, const int* __restrict__ r_seq,
    const float* __restrict__ t_seq, const float* __restrict__ q_tab,
    const float* __restrict__ r_tab,
    const ushort_t* __restrict__ ws1h, const ushort_t* __restrict__ ws1l,
    const float* __restrict__ consth, const float* __restrict__ Ws2,
    const float* __restrict__ bs2, const float* __restrict__ mask,
    ushort_t* __restrict__ h_hi, float* __restrict__ out_ahat) {
    __shared__ ushort_t sQ[33280];     // 64 rows x 1040 B (520 ushorts)
    __shared__ ushort_t sAhi[16384];   // 64 pos x 256 k, blocked
    __shared__ ushort_t sAlo[16384];
    __shared__ float sdiv[128];
    __shared__ float sLogit[64];
    int tid = threadIdx.x;
    if (tid < 128) sdiv[tid] = __expf((float)tid * -0.07195578415606394f); // -ln(10000)/128
    if (tid < 64) sLogit[tid] = 0.0f;
    int w = tid >> 6, lane = tid & 63;
    int pl = lane & 15, kq = lane >> 4;
    int nl = pl;
    int p0 = blockIdx.x * 64;
    int p = p0 + w * 16 + pl;
    int qv = q_seq[p0 + w * 16 + (lane & 15)];
    int rr = r_seq[p];
    float tt = t_seq[p];
    // stage this wave's 16 q-rows into LDS (each async16 = one full 1KB row, coalesced)
#pragma unroll
    for (int i = 0; i < 16; ++i) {
        int row = __shfl(qv, i, 64);
        async16((const ushort_t*)(q_tab + (size_t)row * 256) + lane * 8,
                sQ + (w * 16 + i) * 520);
    }
    __syncthreads();  // q-rows + sdiv + sLogit ready (barrier drains vmcnt)
    const char* myrow = (const char*)sQ + (w * 16 + pl) * 1040;
    const float* rrow = r_tab + (size_t)rr * 256;
#pragma unroll
    for (int it = 0; it < 8; ++it) {
        int kc = it * 4 + kq;
        int k0 = kc * 8;
        float4 qa = *(const float4*)(myrow + kc * 32);
        float4 qb = *(const float4*)(myrow + kc * 32 + 16);
        float4 ra = *(const float4*)(rrow + kc * 8);
        float4 rb = *(const float4*)(rrow + kc * 8 + 4);
        float v[8] = {qa.x + ra.x, qa.y + ra.y, qa.z + ra.z, qa.w + ra.w,
                      qb.x + rb.x, qb.y + rb.y, qb.z + rb.z, qb.w + rb.w};
        bool iscos = (kc >= 16);
#pragma unroll
        for (int j = 0; j < 8; ++j) {
            float ang = tt * sdiv[(k0 + j) & 127];
            v[j] += iscos ? __cosf(ang) : __sinf(ang);
        }
        ushort_t hs[8], ls[8];
#pragma unroll
        for (int j = 0; j < 8; ++j) {
            ushort_t h = f2bf(v[j]);
            hs[j] = h;
            ls[j] = f2bf(v[j] - bf2f(h));
        }
        uint4 hv, lv;
        hv.x = hs[0] | ((uint_t)hs[1] << 16); hv.y = hs[2] | ((uint_t)hs[3] << 16);
        hv.z = hs[4] | ((uint_t)hs[5] << 16); hv.w = hs[6] | ((uint_t)hs[7] << 16);
        lv.x = ls[0] | ((uint_t)ls[1] << 16); lv.y = ls[2] | ((uint_t)ls[3] << 16);
        lv.z = ls[4] | ((uint_t)ls[5] << 16); lv.w = ls[6] | ((uint_t)ls[7] << 16);
        *(uint4*)(h_hi + ((size_t)((blockIdx.x * 4 + w) * 32 + kc) * 16 + pl) * 8) = hv;
        int loff = ((w * 32 + kc) * 16 + pl) * 8;
        *(uint4*)(sAhi + loff) = hv;
        *(uint4*)(sAlo + loff) = lv;
    }
    __syncthreads();  // fragments visible block-wide
    f32x4 acc[4][2];
    f32x4 z4 = {0.f, 0.f, 0.f, 0.f};
#pragma unroll
    for (int mt = 0; mt < 4; ++mt)
#pragma unroll
        for (int nt = 0; nt < 2; ++nt) acc[mt][nt] = z4;
    // software-pipelined B loads from global (L2-hot, coalesced 1KB/wave)
    bf16x8 bhi[2], blo[2], nbhi[2], nblo[2];
#pragma unroll
    for (int nt = 0; nt < 2; ++nt) {
        int off = (((w * 2 + nt) * 32 + kq) * 16 + nl) * 8;
        bhi[nt] = *(const bf16x8*)(ws1h + off);
        blo[nt] = *(const bf16x8*)(ws1l + off);
    }
#pragma unroll 1
    for (int ks = 0; ks < 8; ++ks) {
        if (ks < 7) {
#pragma unroll
            for (int nt = 0; nt < 2; ++nt) {
                int off = (((w * 2 + nt) * 32 + (ks + 1) * 4 + kq) * 16 + nl) * 8;
                nbhi[nt] = *(const bf16x8*)(ws1h + off);
                nblo[nt] = *(const bf16x8*)(ws1l + off);
            }
        }
        bf16x8 ahi[4], alo[4];
#pragma unroll
        for (int mt = 0; mt < 4; ++mt) {
            int off = ((mt * 32 + ks * 4 + kq) * 16 + nl) * 8;
            ahi[mt] = *(const bf16x8*)&sAhi[off];
            alo[mt] = *(const bf16x8*)&sAlo[off];
        }
#pragma unroll
        for (int mt = 0; mt < 4; ++mt)
#pragma unroll
            for (int nt = 0; nt < 2; ++nt) {
                acc[mt][nt] = MFMA16(ahi[mt], bhi[nt], acc[mt][nt]);
                acc[mt][nt] = MFMA16(alo[mt], bhi[nt], acc[mt][nt]);
                acc[mt][nt] = MFMA16(ahi[mt], blo[nt], acc[mt][nt]);
            }
#pragma unroll
        for (int nt = 0; nt < 2; ++nt) { bhi[nt] = nbhi[nt]; blo[nt] = nblo[nt]; }
    }
    // epilogue: hdn = leaky(acc + const_h); partial logits = hdn * Ws2
    float ps[4][4];
#pragma unroll
    for (int mt = 0; mt < 4; ++mt)
#pragma unroll
        for (int r = 0; r < 4; ++r) ps[mt][r] = 0.f;
#pragma unroll
    for (int nt = 0; nt < 2; ++nt) {
        int ng = w * 32 + nt * 16 + nl;
        float chv = consth[ng], w2 = Ws2[ng];
#pragma unroll
        for (int mt = 0; mt < 4; ++mt)
#pragma unroll
            for (int r = 0; r < 4; ++r) {
                float v = acc[mt][nt][r] + chv;
                v = v > 0.f ? v : 0.2f * v;
                ps[mt][r] += v * w2;
            }
    }
#pragma unroll
    for (int mt = 0; mt < 4; ++mt)
#pragma unroll
        for (int r = 0; r < 4; ++r) {
            float x = ps[mt][r];
            x += __shfl_xor(x, 1, 64);
            x += __shfl_xor(x, 2, 64);
            x += __shfl_xor(x, 4, 64);
            x += __shfl_xor(x, 8, 64);
            ps[mt][r] = x;
        }
    if (nl == 0) {
#pragma unroll
        for (int mt = 0; mt < 4; ++mt)
#pragma unroll
            for (int r = 0; r < 4; ++r)
                atomicAdd(&sLogit[mt * 16 + kq * 4 + r], ps[mt][r]);
    }
    __syncthreads();
    if (tid < 64) {
        int pp = p0 + tid;
        float lg = sLogit[tid] + bs2[0];
        float y = lg * 100.0f;
        y = fminf(fmaxf(y, -60.f), 60.f);
        float a = 1.0f / (1.0f + expf(-y));
        out_ahat[pp] = a * mask[pp];
    }
}

// ---------------- K2: Wa GEMM, A-fragments resident in registers (loaded once,
// coalesced dwordx4), B chunk staged in LDS per nch. Fused leaky + A_hat + L-reduce.
__global__ __launch_bounds__(256, 2) void k_agg(
    const ushort_t* __restrict__ h_hi, const ushort_t* __restrict__ wa_blk,
    const float* __restrict__ ba, const float* __restrict__ ahat,
    float* __restrict__ u_i) {
    __shared__ ushort_t sB[32768];  // 128 n x 256 k, blocked
    __shared__ float sAh[128];
    int tid = threadIdx.x;
    int w = tid >> 6, lane = tid & 63, nl = lane & 15, kq = lane >> 4;
    int p0 = blockIdx.x * 128, bidx = p0 >> 11;
    if (tid < 128) sAh[tid] = ahat[p0 + tid];
    int mh = w & 1, nh = w >> 1;
    // A fragments: wave's 64 rows x all 256 K -> 32 coalesced 16B loads
    bf16x8 afr[4][8];
    const ushort_t* gA = h_hi + (size_t)(p0 >> 4) * 4096;
#pragma unroll
    for (int mt = 0; mt < 4; ++mt) {
        const ushort_t* base = gA + (size_t)(mh * 4 + mt) * 4096;
#pragma unroll
        for (int ks = 0; ks < 8; ++ks)
            afr[mt][ks] = *(const bf16x8*)(base + ks * 512 + lane * 8);
    }
#pragma unroll 1
    for (int nch = 0; nch < 8; ++nch) {
        const ushort_t* gB = wa_blk + (size_t)nch * 32768;
#pragma unroll
        for (int i = 0; i < 16; ++i)
            async16(gB + (w * 16 + i) * 512 + lane * 8, sB + (w * 16 + i) * 512);
        __syncthreads();
        f32x4 acc[4][4];
        f32x4 z4 = {0.f, 0.f, 0.f, 0.f};
#pragma unroll
        for (int mt = 0; mt < 4; ++mt)
#pragma unroll
            for (int nt = 0; nt < 4; ++nt) acc[mt][nt] = z4;
#pragma unroll
        for (int ks = 0; ks < 8; ++ks) {
            bf16x8 bfr[4];
#pragma unroll
            for (int nt = 0; nt < 4; ++nt) {
                int ntl = nh * 4 + nt;
                bfr[nt] = *(const bf16x8*)&sB[ntl * 4096 + ks * 512 + lane * 8];
            }
#pragma unroll
            for (int mt = 0; mt < 4; ++mt)
#pragma unroll
                for (int nt = 0; nt < 4; ++nt)
                    acc[mt][nt] = MFMA16(afr[mt][ks], bfr[nt], acc[mt][nt]);
        }
        // epilogue: leaky(acc+ba)*A_hat, reduce over the wave's 64 m-rows
        int n0 = nch * 128;
#pragma unroll
        for (int nt = 0; nt < 4; ++nt) {
            int ng = n0 + nh * 64 + nt * 16 + nl;
            float ban = ba[ng];
            float s = 0.f;
#pragma unroll
            for (int mt = 0; mt < 4; ++mt)
#pragma unroll
                for (int r = 0; r < 4; ++r) {
                    float v = acc[mt][nt][r] + ban;
                    v = v > 0.f ? v : 0.2f * v;
                    int ml = mh * 64 + mt * 16 + kq * 4 + r;
                    s += v * sAh[ml];
                }
            s += __shfl_xor(s, 16, 64);
            s += __shfl_xor(s, 32, 64);
            if (kq == 0) atomicAdd(&u_i[bidx * 1024 + ng], s);
        }
        __syncthreads();  // sB reads complete before next-iter restage
    }
}

extern "C" void kernel_launch(void* const* d_in, const int* in_sizes, int n_in,
                              void* d_out, int out_size, void* d_ws, size_t ws_size,
                              hipStream_t stream) {
    const int* q_seq = (const int*)d_in[0];
    const int* r_seq = (const int*)d_in[1];
    const float* t_seq = (const float*)d_in[2];
    const float* mask = (const float*)d_in[3];
    const float* q_tab = (const float*)d_in[4];
    const float* r_tab = (const float*)d_in[5];
    const float* virt = (const float*)d_in[6];
    const float* Ws1 = (const float*)d_in[7];
    const float* bs1 = (const float*)d_in[8];
    const float* Ws2 = (const float*)d_in[9];
    const float* bs2 = (const float*)d_in[10];
    const float* Wa = (const float*)d_in[11];
    const float* ba = (const float*)d_in[12];
    float* out = (float*)d_out;

    // ws layout
    ushort_t* h_hi = (ushort_t*)d_ws;            // 131072*256 bf16 blocked
    ushort_t* wa_b = h_hi + 33554432;            // 1024*256 bf16 blocked
    ushort_t* ws1h = wa_b + 262144;              // 128*256 bf16 blocked
    ushort_t* ws1l = ws1h + 32768;
    float* ch = (float*)(ws1l + 32768);          // 128 f32

    hipMemsetAsync(out, 0, 65536 * sizeof(float), stream);  // zero u_i
    hipLaunchKernelGGL(k_prep, dim3(145), dim3(256), 0, stream,
                       Ws1, bs1, virt, Wa, ch, wa_b, ws1h, ws1l);
    hipLaunchKernelGGL(k_embed_struct, dim3(2048), dim3(256), 0, stream,
                       q_seq, r_seq, t_seq, q_tab, r_tab, ws1h, ws1l, ch, Ws2, bs2,
                       mask, h_hi, out + 65536);
    hipLaunchKernelGGL(k_agg, dim3(1024), dim3(256), 0, stream,
                       h_hi, wa_b, ba, out + 65536, out);
}

// Round 4
// 259.308 us; speedup vs baseline: 1.2344x; 1.0537x over previous
//
#include <hip/hip_runtime.h>

typedef unsigned short ushort_t;
typedef unsigned int uint_t;

typedef short bf16x8 __attribute__((ext_vector_type(8)));
typedef float f32x4 __attribute__((ext_vector_type(4)));

#define MFMA16(a, b, c) __builtin_amdgcn_mfma_f32_16x16x32_bf16(a, b, c, 0, 0, 0)

__device__ __forceinline__ ushort_t f2bf(float f) {
    uint_t u = __float_as_uint(f);
    u += 0x7fffu + ((u >> 16) & 1u);   // RNE
    return (ushort_t)(u >> 16);
}
__device__ __forceinline__ float bf2f(ushort_t h) {
    return __uint_as_float(((uint_t)h) << 16);
}

// async global->LDS, 16B per lane; lds dst is wave-uniform (HW adds lane*16)
__device__ __forceinline__ void async16(const ushort_t* g, ushort_t* l) {
    __builtin_amdgcn_global_load_lds(
        (const __attribute__((address_space(1))) uint_t*)g,
        (__attribute__((address_space(3))) uint_t*)l, 16, 0, 0);
}

// ---------------- K0: fused prep. block0: const_h; blocks 1..128: Wa->bf16 blocked;
// blocks 129..144: Ws1[:, :256] -> bf16 hi/lo blocked.
// blocked flat (in 8-elem units): ((row/16)*32 + k/8)*16 + row%16
__global__ void k_prep(const float* __restrict__ Ws1, const float* __restrict__ bs1,
                       const float* __restrict__ virt, const float* __restrict__ Wa,
                       float* __restrict__ consth, ushort_t* __restrict__ wa_b,
                       ushort_t* __restrict__ ws1h, ushort_t* __restrict__ ws1l) {
    int b = blockIdx.x;
    if (b == 0) {
        int h = threadIdx.x;
        if (h < 128) {
            const float* row = Ws1 + h * 512 + 256;
            float s = bs1[h];
            for (int d = 0; d < 256; ++d) s += row[d] * virt[d];
            consth[h] = s;
        }
        return;
    }
    const float* src;
    int src_stride, tid;
    ushort_t *dhi, *dlo;
    if (b <= 128) {
        tid = (b - 1) * 256 + threadIdx.x;   // 1024 rows * 32 = 32768 tids
        src = Wa; src_stride = 256; dhi = wa_b; dlo = nullptr;
    } else {
        tid = (b - 129) * 256 + threadIdx.x; // 128 rows * 32 = 4096 tids
        src = Ws1; src_stride = 512; dhi = ws1h; dlo = ws1l;
    }
    int pl = tid & 15, kc = (tid >> 4) & 31, pt = tid >> 9;
    int row = pt * 16 + pl;
    const float* s = src + (size_t)row * src_stride + kc * 8;
    ushort_t hs[8], ls[8];
#pragma unroll
    for (int j = 0; j < 8; ++j) {
        float v = s[j];
        ushort_t h = f2bf(v);
        hs[j] = h;
        ls[j] = f2bf(v - bf2f(h));
    }
    uint4 hv;
    hv.x = hs[0] | ((uint_t)hs[1] << 16); hv.y = hs[2] | ((uint_t)hs[3] << 16);
    hv.z = hs[4] | ((uint_t)hs[5] << 16); hv.w = hs[6] | ((uint_t)hs[7] << 16);
    *(uint4*)(dhi + (size_t)tid * 8) = hv;
    if (dlo) {
        uint4 lv;
        lv.x = ls[0] | ((uint_t)ls[1] << 16); lv.y = ls[2] | ((uint_t)ls[3] << 16);
        lv.z = ls[4] | ((uint_t)ls[5] << 16); lv.w = ls[6] | ((uint_t)ls[7] << 16);
        *(uint4*)(dlo + (size_t)tid * 8) = lv;
    }
}

// ---------------- K1: FUSED embed + struct head.
// LDS region is ALIASED: phase 1-2 it holds the 64 staged q-rows (64x1040B);
// fragments are held in 64 VGPRs across a barrier, then the same region becomes
// sAhi|sAlo for the block-wide MFMA exchange. 67 KB total -> 2 blocks/CU.
__global__ __launch_bounds__(256, 2) void k_embed_struct(
    const int* __restrict__ q_seq, const int* __restrict__ r_seq,
    const float* __restrict__ t_seq, const float* __restrict__ q_tab,
    const float* __restrict__ r_tab,
    const ushort_t* __restrict__ ws1h, const ushort_t* __restrict__ ws1l,
    const float* __restrict__ consth, const float* __restrict__ Ws2,
    const float* __restrict__ bs2, const float* __restrict__ mask,
    ushort_t* __restrict__ h_hi, float* __restrict__ out_ahat) {
    __shared__ __align__(16) char region[66560];   // sQ (64x520 us)  ∪  sAhi+sAlo
    __shared__ float sdiv[128];
    __shared__ float sLogit[64];
    ushort_t* sQ = (ushort_t*)region;
    ushort_t* sAhi = (ushort_t*)region;
    ushort_t* sAlo = (ushort_t*)(region + 32768);
    int tid = threadIdx.x;
    if (tid < 128) sdiv[tid] = __expf((float)tid * -0.07195578415606394f); // -ln(10000)/128
    if (tid < 64) sLogit[tid] = 0.0f;
    int w = tid >> 6, lane = tid & 63;
    int pl = lane & 15, kq = lane >> 4;
    int nl = pl;
    int p0 = blockIdx.x * 64;
    int p = p0 + w * 16 + pl;
    int qv = q_seq[p0 + w * 16 + pl];
    int rr = r_seq[p];
    float tt = t_seq[p];
    // stage this wave's 16 q-rows into LDS (each async16 = one full 1KB row, coalesced)
#pragma unroll
    for (int i = 0; i < 16; ++i) {
        int row = __shfl(qv, i, 64);
        async16((const ushort_t*)(q_tab + (size_t)row * 256) + lane * 8,
                sQ + (w * 16 + i) * 520);
    }
    __syncthreads();  // q-rows + sdiv + sLogit ready (barrier drains vmcnt)
    // phase 2: compute fragments into REGISTERS (sQ still live)
    uint4 hvA[8], lvA[8];
    const char* myrow = (const char*)sQ + (w * 16 + pl) * 1040;
    const float* rrow = r_tab + (size_t)rr * 256;
#pragma unroll
    for (int it = 0; it < 8; ++it) {
        int kc = it * 4 + kq;
        int k0 = kc * 8;
        float4 qa = *(const float4*)(myrow + kc * 32);
        float4 qb = *(const float4*)(myrow + kc * 32 + 16);
        float4 ra = *(const float4*)(rrow + kc * 8);
        float4 rb = *(const float4*)(rrow + kc * 8 + 4);
        float v[8] = {qa.x + ra.x, qa.y + ra.y, qa.z + ra.z, qa.w + ra.w,
                      qb.x + rb.x, qb.y + rb.y, qb.z + rb.z, qb.w + rb.w};
        bool iscos = (kc >= 16);
#pragma unroll
        for (int j = 0; j < 8; ++j) {
            float ang = tt * sdiv[(k0 + j) & 127];
            v[j] += iscos ? __cosf(ang) : __sinf(ang);
        }
        ushort_t hs[8], ls[8];
#pragma unroll
        for (int j = 0; j < 8; ++j) {
            ushort_t h = f2bf(v[j]);
            hs[j] = h;
            ls[j] = f2bf(v[j] - bf2f(h));
        }
        uint4 hv, lv;
        hv.x = hs[0] | ((uint_t)hs[1] << 16); hv.y = hs[2] | ((uint_t)hs[3] << 16);
        hv.z = hs[4] | ((uint_t)hs[5] << 16); hv.w = hs[6] | ((uint_t)hs[7] << 16);
        lv.x = ls[0] | ((uint_t)ls[1] << 16); lv.y = ls[2] | ((uint_t)ls[3] << 16);
        lv.z = ls[4] | ((uint_t)ls[5] << 16); lv.w = ls[6] | ((uint_t)ls[7] << 16);
        hvA[it] = hv; lvA[it] = lv;
        *(uint4*)(h_hi + ((size_t)((blockIdx.x * 4 + w) * 32 + kc) * 16 + pl) * 8) = hv;
    }
    __syncthreads();  // all sQ reads complete -> region can be re-purposed
#pragma unroll
    for (int it = 0; it < 8; ++it) {
        int kc = it * 4 + kq;
        int loff = ((w * 32 + kc) * 16 + pl) * 8;
        *(uint4*)(sAhi + loff) = hvA[it];
        *(uint4*)(sAlo + loff) = lvA[it];
    }
    __syncthreads();  // fragments visible block-wide
    f32x4 acc[4][2];
    f32x4 z4 = {0.f, 0.f, 0.f, 0.f};
#pragma unroll
    for (int mt = 0; mt < 4; ++mt)
#pragma unroll
        for (int nt = 0; nt < 2; ++nt) acc[mt][nt] = z4;
    // software-pipelined B loads from global (L2-hot, coalesced 1KB/wave)
    bf16x8 bhi[2], blo[2], nbhi[2], nblo[2];
#pragma unroll
    for (int nt = 0; nt < 2; ++nt) {
        int off = (((w * 2 + nt) * 32 + kq) * 16 + nl) * 8;
        bhi[nt] = *(const bf16x8*)(ws1h + off);
        blo[nt] = *(const bf16x8*)(ws1l + off);
    }
#pragma unroll 1
    for (int ks = 0; ks < 8; ++ks) {
        if (ks < 7) {
#pragma unroll
            for (int nt = 0; nt < 2; ++nt) {
                int off = (((w * 2 + nt) * 32 + (ks + 1) * 4 + kq) * 16 + nl) * 8;
                nbhi[nt] = *(const bf16x8*)(ws1h + off);
                nblo[nt] = *(const bf16x8*)(ws1l + off);
            }
        }
        bf16x8 ahi[4], alo[4];
#pragma unroll
        for (int mt = 0; mt < 4; ++mt) {
            int off = ((mt * 32 + ks * 4 + kq) * 16 + nl) * 8;
            ahi[mt] = *(const bf16x8*)&sAhi[off];
            alo[mt] = *(const bf16x8*)&sAlo[off];
        }
#pragma unroll
        for (int mt = 0; mt < 4; ++mt)
#pragma unroll
            for (int nt = 0; nt < 2; ++nt) {
                acc[mt][nt] = MFMA16(ahi[mt], bhi[nt], acc[mt][nt]);
                acc[mt][nt] = MFMA16(alo[mt], bhi[nt], acc[mt][nt]);
                acc[mt][nt] = MFMA16(ahi[mt], blo[nt], acc[mt][nt]);
            }
#pragma unroll
        for (int nt = 0; nt < 2; ++nt) { bhi[nt] = nbhi[nt]; blo[nt] = nblo[nt]; }
    }
    // epilogue: hdn = leaky(acc + const_h); partial logits = hdn * Ws2
    float ps[4][4];
#pragma unroll
    for (int mt = 0; mt < 4; ++mt)
#pragma unroll
        for (int r = 0; r < 4; ++r) ps[mt][r] = 0.f;
#pragma unroll
    for (int nt = 0; nt < 2; ++nt) {
        int ng = w * 32 + nt * 16 + nl;
        float chv = consth[ng], w2 = Ws2[ng];
#pragma unroll
        for (int mt = 0; mt < 4; ++mt)
#pragma unroll
            for (int r = 0; r < 4; ++r) {
                float v = acc[mt][nt][r] + chv;
                v = v > 0.f ? v : 0.2f * v;
                ps[mt][r] += v * w2;
            }
    }
#pragma unroll
    for (int mt = 0; mt < 4; ++mt)
#pragma unroll
        for (int r = 0; r < 4; ++r) {
            float x = ps[mt][r];
            x += __shfl_xor(x, 1, 64);
            x += __shfl_xor(x, 2, 64);
            x += __shfl_xor(x, 4, 64);
            x += __shfl_xor(x, 8, 64);
            ps[mt][r] = x;
        }
    if (nl == 0) {
#pragma unroll
        for (int mt = 0; mt < 4; ++mt)
#pragma unroll
            for (int r = 0; r < 4; ++r)
                atomicAdd(&sLogit[mt * 16 + kq * 4 + r], ps[mt][r]);
    }
    __syncthreads();
    if (tid < 64) {
        int pp = p0 + tid;
        float lg = sLogit[tid] + bs2[0];
        float y = lg * 100.0f;
        y = fminf(fmaxf(y, -60.f), 60.f);
        float a = 1.0f / (1.0f + expf(-y));
        out_ahat[pp] = a * mask[pp];
    }
}

// ---------------- K2: Wa GEMM, A-fragments resident in registers (loaded once,
// coalesced dwordx4); B double-buffered in 2x32KB LDS halves with issue-early
// async staging (DMA overlaps MFMA). Fused leaky + A_hat + L-reduce.
__global__ __launch_bounds__(256, 2) void k_agg(
    const ushort_t* __restrict__ h_hi, const ushort_t* __restrict__ wa_blk,
    const float* __restrict__ ba, const float* __restrict__ ahat,
    float* __restrict__ u_i) {
    __shared__ ushort_t sB[2][16384];  // each: [t 0..7][kcl 0..15][nl 0..15][8]
    __shared__ float sAh[128];
    int tid = threadIdx.x;
    int w = tid >> 6, lane = tid & 63, nl = lane & 15, kq = lane >> 4;
    int p0 = blockIdx.x * 128, bidx = p0 >> 11;
    if (tid < 128) sAh[tid] = ahat[p0 + tid];
    int mh = w & 1, nh = w >> 1;
    // A fragments: wave's 64 rows x all 256 K -> 32 coalesced 16B loads
    bf16x8 afr[4][8];
    const ushort_t* gA = h_hi + (size_t)(p0 >> 4) * 4096;
#pragma unroll
    for (int mt = 0; mt < 4; ++mt) {
        const ushort_t* base = gA + (size_t)(mh * 4 + mt) * 4096;
#pragma unroll
        for (int ks = 0; ks < 8; ++ks)
            afr[mt][ks] = *(const bf16x8*)(base + ks * 512 + lane * 8);
    }
    // stage-half macro: nch, kh -> buf.  per wave: 2 ntiles x 4 KB (4 async16 each)
#define STAGE_HALF(buf, nch_, kh_)                                              \
    {                                                                           \
        int t0 = w * 2;                                                         \
        _Pragma("unroll")                                                       \
        for (int tt = 0; tt < 2; ++tt) {                                        \
            int t = t0 + tt;                                                    \
            const ushort_t* src =                                               \
                wa_blk + (size_t)((nch_) * 8 + t) * 4096 + (kh_) * 2048;        \
            _Pragma("unroll")                                                   \
            for (int c = 0; c < 4; ++c)                                         \
                async16(src + c * 512 + lane * 8, &sB[buf][t * 2048 + c * 512]);\
        }                                                                       \
    }
    f32x4 acc[4][4];
    f32x4 z4 = {0.f, 0.f, 0.f, 0.f};
#pragma unroll
    for (int mt = 0; mt < 4; ++mt)
#pragma unroll
        for (int nt = 0; nt < 4; ++nt) acc[mt][nt] = z4;
    STAGE_HALF(0, 0, 0);
    __syncthreads();  // sB[0] (nch0,kh0) + sAh ready
#pragma unroll 1
    for (int nch = 0; nch < 8; ++nch) {
        // ---- kh = 0: compute on sB[0], prefetch (nch,1) into sB[1]
        STAGE_HALF(1, nch, 1);
#pragma unroll
        for (int ksl = 0; ksl < 4; ++ksl) {
            bf16x8 bfr[4];
#pragma unroll
            for (int nt = 0; nt < 4; ++nt)
                bfr[nt] = *(const bf16x8*)&sB[0][(nh * 4 + nt) * 2048 + (ksl * 4 + kq) * 128 + nl * 8];
#pragma unroll
            for (int mt = 0; mt < 4; ++mt)
#pragma unroll
                for (int nt = 0; nt < 4; ++nt)
                    acc[mt][nt] = MFMA16(afr[mt][ksl], bfr[nt], acc[mt][nt]);
        }
        __syncthreads();  // sB[1] staged; sB[0] reads done
        // ---- kh = 1: compute on sB[1], prefetch (nch+1,0) into sB[0]
        if (nch < 7) STAGE_HALF(0, nch + 1, 0);
#pragma unroll
        for (int ksl = 0; ksl < 4; ++ksl) {
            bf16x8 bfr[4];
#pragma unroll
            for (int nt = 0; nt < 4; ++nt)
                bfr[nt] = *(const bf16x8*)&sB[1][(nh * 4 + nt) * 2048 + (ksl * 4 + kq) * 128 + nl * 8];
#pragma unroll
            for (int mt = 0; mt < 4; ++mt)
#pragma unroll
                for (int nt = 0; nt < 4; ++nt)
                    acc[mt][nt] = MFMA16(afr[mt][4 + ksl], bfr[nt], acc[mt][nt]);
        }
        __syncthreads();  // sB[0] staged; sB[1] reads done
        // ---- epilogue for this nch (overlaps next staging already in flight)
        int n0 = nch * 128;
#pragma unroll
        for (int nt = 0; nt < 4; ++nt) {
            int ng = n0 + nh * 64 + nt * 16 + nl;
            float ban = ba[ng];
            float s = 0.f;
#pragma unroll
            for (int mt = 0; mt < 4; ++mt)
#pragma unroll
                for (int r = 0; r < 4; ++r) {
                    float v = acc[mt][nt][r] + ban;
                    v = v > 0.f ? v : 0.2f * v;
                    int ml = mh * 64 + mt * 16 + kq * 4 + r;
                    s += v * sAh[ml];
                    acc[mt][nt][r] = 0.f;
                }
            s += __shfl_xor(s, 16, 64);
            s += __shfl_xor(s, 32, 64);
            if (kq == 0) atomicAdd(&u_i[bidx * 1024 + ng], s);
        }
    }
#undef STAGE_HALF
}

extern "C" void kernel_launch(void* const* d_in, const int* in_sizes, int n_in,
                              void* d_out, int out_size, void* d_ws, size_t ws_size,
                              hipStream_t stream) {
    const int* q_seq = (const int*)d_in[0];
    const int* r_seq = (const int*)d_in[1];
    const float* t_seq = (const float*)d_in[2];
    const float* mask = (const float*)d_in[3];
    const float* q_tab = (const float*)d_in[4];
    const float* r_tab = (const float*)d_in[5];
    const float* virt = (const float*)d_in[6];
    const float* Ws1 = (const float*)d_in[7];
    const float* bs1 = (const float*)d_in[8];
    const float* Ws2 = (const float*)d_in[9];
    const float* bs2 = (const float*)d_in[10];
    const float* Wa = (const float*)d_in[11];
    const float* ba = (const float*)d_in[12];
    float* out = (float*)d_out;

    // ws layout
    ushort_t* h_hi = (ushort_t*)d_ws;            // 131072*256 bf16 blocked
    ushort_t* wa_b = h_hi + 33554432;            // 1024*256 bf16 blocked
    ushort_t* ws1h = wa_b + 262144;              // 128*256 bf16 blocked
    ushort_t* ws1l = ws1h + 32768;
    float* ch = (float*)(ws1l + 32768);          // 128 f32

    hipMemsetAsync(out, 0, 65536 * sizeof(float), stream);  // zero u_i
    hipLaunchKernelGGL(k_prep, dim3(145), dim3(256), 0, stream,
                       Ws1, bs1, virt, Wa, ch, wa_b, ws1h, ws1l);
    hipLaunchKernelGGL(k_embed_struct, dim3(2048), dim3(256), 0, stream,
                       q_seq, r_seq, t_seq, q_tab, r_tab, ws1h, ws1l, ch, Ws2, bs2,
                       mask, h_hi, out + 65536);
    hipLaunchKernelGGL(k_agg, dim3(1024), dim3(256), 0, stream,
                       h_hi, wa_b, ba, out + 65536, out);
}